// Round 12
// baseline (789.347 us; speedup 1.0000x reference)
//
#include <hip/hip_runtime.h>

#define MNODES 50000
#define M_PAD  50048          // 391 * 128
#define NEDGES 800000
#define DIN    128
#define DD     256
#define D2     512
#define NLAYERS 3
#define BN_EPS 1e-5f
#define NREP   16             // stats replica rows (contention spreader)

typedef unsigned short ushort_t;
typedef __bf16 v8bf __attribute__((ext_vector_type(8)));
typedef unsigned short v8us __attribute__((ext_vector_type(8)));
typedef float  v4f  __attribute__((ext_vector_type(4)));

#define GLOBAL_AS __attribute__((address_space(1)))
#define LDS_AS    __attribute__((address_space(3)))

__device__ __forceinline__ float bf2f(ushort_t u) {
    unsigned x = ((unsigned)u) << 16;
    return __uint_as_float(x);
}
__device__ __forceinline__ ushort_t f2bf(float f) {
    unsigned u = __float_as_uint(f);
    u += 0x7FFF + ((u >> 16) & 1);   // RNE
    return (ushort_t)(u >> 16);
}
__device__ __forceinline__ void async16(const ushort_t* g, ushort_t* l) {
    __builtin_amdgcn_global_load_lds((const GLOBAL_AS unsigned int*)g,
                                     (LDS_AS unsigned int*)l, 16, 0, 0);
}
// bijective XCD-chunked remap (kept from r11: neutral-measured, in principle
// aligns producer writes with consumer reads per XCD L2)
__device__ __forceinline__ int xcd_chunk(int b, int nb) {
    int q = nb >> 3, r = nb & 7, x = b & 7, s = b >> 3;
    return (x < r ? x * (q + 1) : r * (q + 1) + (x - r) * q) + s;
}
#define BARRIER() asm volatile("s_barrier" ::: "memory")
#define VMWAIT6() asm volatile("s_waitcnt vmcnt(6)" ::: "memory")
#define VMWAIT2() asm volatile("s_waitcnt vmcnt(2)" ::: "memory")
#define VMWAIT0() asm volatile("s_waitcnt vmcnt(0)" ::: "memory")
#define LGKM0()   asm volatile("s_waitcnt lgkmcnt(0)" ::: "memory")

// ------- fused prep: weight transpose tiles (blocks 0..799) + bf16 cast + inits
#define R0 (M_PAD * DIN)                       // 6406144
#define R0V (R0 / 4)                           // 1601536 (float4/ushort4 path)
#define NCASTB (R0V / 256)                     // 6256 cast blocks (exact)
#define NSTATZ (NREP * D2 * 2 + NREP * DD * 2) // 24576 floats (contiguous slabs)
#define NWTB 800                               // 32 + 3*128 + 3*128 transpose tiles
__global__ __launch_bounds__(256)
void k_prep_all(const float* __restrict__ pre, ushort_t* __restrict__ preb,
                const float* __restrict__ W0, const float* __restrict__ W1,
                const float* __restrict__ W2, ushort_t* __restrict__ W0T,
                ushort_t* __restrict__ W1T, ushort_t* __restrict__ W2T,
                float* __restrict__ caf, float* __restrict__ ccf,
                float* __restrict__ statz, int* __restrict__ deg) {
    __shared__ float tl[32][33];
    if (blockIdx.x < NWTB) {       // 32x32 LDS-tiled transpose, coalesced both sides
        int tile = blockIdx.x;
        const float* src; ushort_t* dst; int K, N;
        if (tile < 32) {
            src = W0; dst = W0T; K = DIN; N = DD;
        } else if (tile < 416) {
            int t2 = tile - 32, l = t2 >> 7; t2 &= 127;
            src = W1 + (size_t)l * DD * D2; dst = W1T + (size_t)l * DD * D2;
            K = DD; N = D2; tile = t2;
        } else {
            int t2 = tile - 416, l = t2 >> 7; t2 &= 127;
            src = W2 + (size_t)l * D2 * DD; dst = W2T + (size_t)l * D2 * DD;
            K = D2; N = DD; tile = t2;
        }
        int ntn = N >> 5;
        int kt = tile / ntn, nt = tile - kt * ntn;
        int tx = threadIdx.x & 31, ty = threadIdx.x >> 5;   // 8 rows/phase
        #pragma unroll
        for (int r = 0; r < 4; r++)
            tl[ty + 8 * r][tx] = src[(size_t)(kt * 32 + ty + 8 * r) * N + nt * 32 + tx];
        __syncthreads();
        #pragma unroll
        for (int r = 0; r < 4; r++)
            dst[(size_t)(nt * 32 + ty + 8 * r) * K + kt * 32 + tx] =
                f2bf(tl[tx][ty + 8 * r]);
        return;
    }
    int b2 = blockIdx.x - NWTB;
    if (b2 < NCASTB) {              // cast, XCD-chunked
        int i = xcd_chunk(b2, NCASTB) * 256 + threadIdx.x;
        int row = i >> 5;           // 32 ushort4 per row
        ushort4 o;
        if (row < MNODES) {
            float4 v = ((const float4*)pre)[i];
            o.x = f2bf(v.x); o.y = f2bf(v.y); o.z = f2bf(v.z); o.w = f2bf(v.w);
        } else {
            o.x = 0; o.y = 0; o.z = 0; o.w = 0;
        }
        ((ushort4*)preb)[i] = o;
        return;
    }
    int j = (b2 - NCASTB) * 256 + threadIdx.x;
    if (j < 256) { caf[j] = 1.f; ccf[j] = 0.f; return; }
    j -= 256;
    if (j < NSTATZ) { statz[j] = 0.f; return; }
    j -= NSTATZ;
    if (j < MNODES) deg[j] = 0;
}

// ---------------- CSR build ----------------
__global__ void k_hist(const int* __restrict__ ei, int* __restrict__ deg) {
    int e = blockIdx.x * blockDim.x + threadIdx.x;
    if (e < NEDGES) atomicAdd(&deg[ei[e * 2 + 1]], 1);
}
__global__ void k_scan1(const int* __restrict__ deg, int* __restrict__ rowptr,
                        int* __restrict__ bsum, int n) {
    __shared__ int tmp[256];
    int tid = threadIdx.x;
    int i = blockIdx.x * 256 + tid;
    int v = (i < n) ? deg[i] : 0;
    tmp[tid] = v;
    __syncthreads();
    #pragma unroll
    for (int off = 1; off < 256; off <<= 1) {
        int t = (tid >= off) ? tmp[tid - off] : 0;
        __syncthreads();
        tmp[tid] += t;
        __syncthreads();
    }
    if (i < n) rowptr[i + 1] = tmp[tid];
    if (tid == 255) bsum[blockIdx.x] = tmp[255];
}
__global__ __launch_bounds__(256)
void k_scan2(int* __restrict__ bsum, int nb) {
    __shared__ int tmp[256];
    int tid = threadIdx.x;
    int v = (tid < nb) ? bsum[tid] : 0;
    tmp[tid] = v;
    __syncthreads();
    #pragma unroll
    for (int off = 1; off < 256; off <<= 1) {
        int t = (tid >= off) ? tmp[tid - off] : 0;
        __syncthreads();
        tmp[tid] += t;
        __syncthreads();
    }
    if (tid < nb) bsum[tid] = tmp[tid] - v;
}
__global__ void k_scan3(const int* __restrict__ deg, const int* __restrict__ bsum,
                        int* __restrict__ rowptr, int* __restrict__ cursor, int n) {
    int i = blockIdx.x * 256 + threadIdx.x;
    if (i == 0) rowptr[0] = 0;
    if (i < n) {
        int incl = rowptr[i + 1] + bsum[i >> 8];
        rowptr[i + 1] = incl;
        cursor[i] = incl - deg[i];
    }
}
__global__ void k_fill(const int* __restrict__ ei, int* __restrict__ cursor,
                       int* __restrict__ col) {
    int e = blockIdx.x * blockDim.x + threadIdx.x;
    if (e < NEDGES) {
        int pos = atomicAdd(&cursor[ei[e * 2 + 1]], 1);
        col[pos] = ei[e * 2];
    }
}

// --- gather: out = ca*(x[n] + sum x[src]) + (deg+1)*cc; masked 8-deep loop ---
__global__ void k_gather(const int* __restrict__ rowptr, const int* __restrict__ col,
                         const ushort_t* __restrict__ x, const float* __restrict__ ca,
                         const float* __restrict__ cc, ushort_t* __restrict__ out) {
    int node = xcd_chunk(blockIdx.x, MNODES / 4) * 4 + (threadIdx.x >> 6);
    int lane = threadIdx.x & 63;
    if (node >= MNODES) return;
    const ushort4* xp = (const ushort4*)x;
    ushort4 v = xp[(size_t)node * 64 + lane];
    float a0 = bf2f(v.x), a1 = bf2f(v.y), a2 = bf2f(v.z), a3 = bf2f(v.w);
    int s = rowptr[node], e = rowptr[node + 1];
    for (int i = s; i < e; i += 8) {
        ushort4 u[8];
        float m[8];
        #pragma unroll
        for (int j = 0; j < 8; j++) {
            int idx = i + j;
            int cj = col[idx < e ? idx : e - 1];   // e>s inside loop -> e-1 valid
            m[j] = (idx < e) ? 1.f : 0.f;
            u[j] = xp[(size_t)cj * 64 + lane];
        }
        #pragma unroll
        for (int j = 0; j < 8; j++) {
            a0 = fmaf(m[j], bf2f(u[j].x), a0);
            a1 = fmaf(m[j], bf2f(u[j].y), a1);
            a2 = fmaf(m[j], bf2f(u[j].z), a2);
            a3 = fmaf(m[j], bf2f(u[j].w), a3);
        }
    }
    int c = lane * 4;
    float dn = (float)(e - s) + 1.0f;
    ushort4 o;
    o.x = f2bf(ca[c + 0] * a0 + dn * cc[c + 0]);
    o.y = f2bf(ca[c + 1] * a1 + dn * cc[c + 1]);
    o.z = f2bf(ca[c + 2] * a2 + dn * cc[c + 2]);
    o.w = f2bf(ca[c + 3] * a3 + dn * cc[c + 3]);
    ((ushort4*)out)[(size_t)node * 64 + lane] = o;
}

// ---------------- BN coeffs: fold NREP replicas, re-zero them ----------------
__global__ void k_coeffs(float* __restrict__ sums, float* __restrict__ sumsq,
                         const float* __restrict__ g, const float* __restrict__ beta,
                         float* __restrict__ ca, float* __restrict__ cc,
                         float2* __restrict__ cacc, int n) {
    int c = blockIdx.x * blockDim.x + threadIdx.x;
    if (c >= n) return;
    float s = 0.f, q = 0.f;
    #pragma unroll
    for (int r = 0; r < NREP; r++) {
        s += sums[r * n + c];  sums[r * n + c]  = 0.f;
        q += sumsq[r * n + c]; sumsq[r * n + c] = 0.f;
    }
    float mean = s * (1.0f / MNODES);
    float var  = q * (1.0f / MNODES) - mean * mean;
    float a    = g[c] * rsqrtf(var + BN_EPS);
    float b    = beta[c] - a * mean;
    ca[c] = a;
    cc[c] = b;
    if (cacc) cacc[c] = make_float2(a, b);
}

// ------ final: d_out = ca*h + cc (fp32) ------
__global__ void k_apply_out(const ushort_t* __restrict__ h, const float* __restrict__ ca,
                            const float* __restrict__ cc, float* __restrict__ out) {
    int i = xcd_chunk(blockIdx.x, (MNODES * 64) / 256) * 256 + threadIdx.x;
    int c = (i & 63) * 4;
    ushort4 v = ((const ushort4*)h)[i];
    float4 o;
    o.x = ca[c + 0] * bf2f(v.x) + cc[c + 0];
    o.y = ca[c + 1] * bf2f(v.y) + cc[c + 1];
    o.z = ca[c + 2] * bf2f(v.z) + cc[c + 2];
    o.w = ca[c + 3] * bf2f(v.w) + cc[c + 3];
    ((float4*)out)[i] = o;
}

// ---- B-dbuf bf16 MFMA GEMM, 256x128 tile, 512 threads / 8 waves ----
// Per-wave code identical to r7's proven 32-row-strip schedule; the NEW axis
// (untried in 8 prior variants, all 256-thread) is TLP: 8 waves share one
// 32 KB B-tile -> 24 waves/CU resident (vs 16), half the block count, half
// the B-DMA per unit work. vmcnt re-derived for 2 DMAs/chunk/wave:
//   prologue: A-ring(8) chunk0(2) chunk1(2) -> drain A+chunk0 = vmcnt(2)
//   counted boundary (full unroll, k=4 A-prefetches guaranteed since
//   2c+3 < nk for all c <= nc2-2): oldest 2 = chunk c; newer = 4A + 2 new
//   DMA -> vmcnt(6). Last boundary vmcnt(0).
#define LOADA(buf, st)                                                        \
    { buf[0] = *(const v8bf*)(Ap + (st) * 32);                                \
      buf[1] = *(const v8bf*)(Ap + 16 * KT + (st) * 32); }

template<int DO_STATS, int RES, int FUSE_BN, int KT>
__global__ __launch_bounds__(512, 3)
void k_gemm_bf(const ushort_t* __restrict__ A, const ushort_t* __restrict__ WT,
               const float* __restrict__ bias,
               const ushort_t* resid, const float* __restrict__ r_ca,
               const float* __restrict__ r_cc, const float2* __restrict__ cacc,
               ushort_t* out, float* __restrict__ sums, float* __restrict__ sumsq,
               int M, int N) {
    static_assert(KT % 128 == 0, "KT multiple of 128");
    constexpr int nk  = KT >> 5;         // K-steps: 4, 8, 16
    constexpr int nc2 = KT >> 6;         // 64k chunks: 2, 4, 8
    __shared__ __align__(16) ushort_t Bs[2][128 * 64];   // 2 x 16 KB
    const int tid = threadIdx.x;
    const int w = tid >> 6, lane = tid & 63;             // w in 0..7
    const int quad = lane >> 4, l15 = lane & 15;

    // bijective XCD-chunked swizzle
    const int nxb = N >> 7;                         // 2 or 4 (power of two)
    const int nwg = nxb * (int)gridDim.y;
    const int orig = (int)blockIdx.y * nxb + (int)blockIdx.x;
    const int swz = xcd_chunk(orig, nwg);
    const int bx = swz & (nxb - 1);
    const int by = (nxb == 4) ? (swz >> 2) : (swz >> 1);
    const int m0 = by * 256, n0 = bx * 128;

    // FUSE_BN: stage interleaved (ca,cc) per-k into a small LDS table once.
    float2* cacc_lds = nullptr;
    if constexpr (FUSE_BN != 0) {
        __shared__ __align__(16) float2 cacc_s[KT];
        cacc_lds = cacc_s;
        for (int k2 = tid; k2 < KT; k2 += 512) cacc_lds[k2] = cacc[k2];
        // cross-wave visibility: LGKM0 + prologue barrier below
    }

    // B DMA sources: per wave 2 issues/chunk; issue ii = w*2+j covers rows
    // ii*8 + (lane>>3); lane slot lane&7 holds global chunk (lane&7)^(row&7).
    const ushort_t* srcB[2];
    {
        int r8 = lane >> 3, s8 = lane & 7;
        #pragma unroll
        for (int j = 0; j < 2; j++) {
            int rowb = (w * 2 + j) * 8 + r8;
            int g = s8 ^ (rowb & 7);
            srcB[j] = WT + (size_t)(n0 + rowb) * KT + g * 8;
        }
    }

    // per-wave private A strip: rows m0 + w*32 .. +32 (8 waves cover 256 rows)
    const ushort_t* Ap = A + (size_t)(m0 + w * 32 + l15) * KT + quad * 8;

    v4f acc[2][8];
    #pragma unroll
    for (int i = 0; i < 2; i++)
        #pragma unroll
        for (int j = 0; j < 8; j++)
            acc[i][j] = (v4f){0.f, 0.f, 0.f, 0.f};

    // A prologue: 4-slot ring holds steps 0..3 (nk >= 4 always)
    v8bf a0[2], a1[2], a2[2], a3[2];
    LOADA(a0, 0) LOADA(a1, 1) LOADA(a2, 2) LOADA(a3, 3)

    // B prologue: chunks 0 and 1 (nc2 >= 2 always)
    #pragma unroll
    for (int j = 0; j < 2; j++) async16(srcB[j], &Bs[0][(w * 2 + j) * 512]);
    #pragma unroll
    for (int j = 0; j < 2; j++) async16(srcB[j] + 64, &Bs[1][(w * 2 + j) * 512]);
    if constexpr (FUSE_BN != 0) { LGKM0(); }
    VMWAIT2();                    // drain A + chunk0; chunk1 (2) stays in flight
    BARRIER();

    #pragma unroll
    for (int c = 0; c < nc2; c++) {
        if (c > 0) {
            BARRIER();            // all waves done reading Bs[(c-1)&1] — freed
            if (c + 1 < nc2) {
                #pragma unroll
                for (int j = 0; j < 2; j++)
                    async16(srcB[j] + (c + 1) * 64, &Bs[(c + 1) & 1][(w * 2 + j) * 512]);
                VMWAIT6();        // chunk c's 2 DMAs (oldest) retired;
                                  // 4 A-prefetch + 2 new DMAs stay in flight
            } else {
                VMWAIT0();        // last chunk: full drain
            }
            BARRIER();            // chunk c visible to all waves
        }
        const ushort_t* Bb = Bs[c & 1];
        #pragma unroll
        for (int tc = 0; tc < 2; tc++) {
            const int s = c * 2 + tc;
            const int sl4 = s & 3;
            v8bf aUse[2];
            if (sl4 == 0)      { aUse[0] = a0[0]; aUse[1] = a0[1]; }
            else if (sl4 == 1) { aUse[0] = a1[0]; aUse[1] = a1[1]; }
            else if (sl4 == 2) { aUse[0] = a2[0]; aUse[1] = a2[1]; }
            else               { aUse[0] = a3[0]; aUse[1] = a3[1]; }
            if (s + 4 < nk) {
                if (sl4 == 0)      { LOADA(a0, s + 4) }
                else if (sl4 == 1) { LOADA(a1, s + 4) }
                else if (sl4 == 2) { LOADA(a2, s + 4) }
                else               { LOADA(a3, s + 4) }
            }
            if constexpr (FUSE_BN != 0) {
                const float* cb = (const float*)&cacc_lds[(s << 5) + (quad << 3)];
                #pragma unroll
                for (int mt = 0; mt < 2; mt++) {
                    v8us au = *(v8us*)&aUse[mt];
                    v8bf o;
                    #pragma unroll
                    for (int j = 0; j < 8; j++) {
                        float h = bf2f(au[j]);
                        o[j] = (__bf16)fmaxf(fmaf(cb[2 * j], h, cb[2 * j + 1]), 0.f);
                    }
                    aUse[mt] = o;
                }
            }
            v8bf bb0[4];
            #pragma unroll
            for (int nt = 0; nt < 4; nt++) {
                int n_l = nt * 16 + l15;
                int slot = (tc * 4 + quad) ^ (n_l & 7);
                bb0[nt] = *(const v8bf*)&Bb[n_l * 64 + slot * 8];
            }
            #pragma unroll
            for (int mt = 0; mt < 2; mt++)
                #pragma unroll
                for (int nt = 0; nt < 4; nt++)
                    acc[mt][nt] = __builtin_amdgcn_mfma_f32_16x16x32_bf16(
                        aUse[mt], bb0[nt], acc[mt][nt], 0, 0, 0);
            v8bf bb1[4];
            #pragma unroll
            for (int nt = 0; nt < 4; nt++) {
                int n_l = (nt + 4) * 16 + l15;
                int slot = (tc * 4 + quad) ^ (n_l & 7);
                bb1[nt] = *(const v8bf*)&Bb[n_l * 64 + slot * 8];
            }
            #pragma unroll
            for (int mt = 0; mt < 2; mt++)
                #pragma unroll
                for (int nt = 0; nt < 4; nt++)
                    acc[mt][nt + 4] = __builtin_amdgcn_mfma_f32_16x16x32_bf16(
                        aUse[mt], bb1[nt], acc[mt][nt + 4], 0, 0, 0);
        }
    }

    // epilogue: bias (+ lazy-BN residual) -> bf16 store + fused column stats
    const int mlim = M - m0;
    float s_sum[8], s_sq[8];
    #pragma unroll
    for (int nt = 0; nt < 8; nt++) { s_sum[nt] = 0.f; s_sq[nt] = 0.f; }
    #pragma unroll
    for (int nt = 0; nt < 8; nt++) {
        int colg = n0 + nt * 16 + l15;
        float bia = bias[colg];
        float rca = 0.f, rcc = 0.f;
        if (RES) { rca = r_ca[colg]; rcc = r_cc[colg]; }
        #pragma unroll
        for (int mt = 0; mt < 2; mt++) {
            int rbase = w * 32 + mt * 16 + quad * 4;
            #pragma unroll
            for (int r = 0; r < 4; r++) {
                int rl = rbase + r;
                if (rl < mlim) {
                    size_t idx = (size_t)(m0 + rl) * N + colg;
                    float v = acc[mt][nt][r] + bia;
                    if (RES) v += rca * bf2f(resid[idx]) + rcc;
                    out[idx] = f2bf(v);
                    if (DO_STATS) { s_sum[nt] += v; s_sq[nt] += v * v; }
                }
            }
        }
    }
    if (DO_STATS) {
        const int rep = (by * 8 + w) & (NREP - 1);
        #pragma unroll
        for (int nt = 0; nt < 8; nt++) {
            float s = s_sum[nt], q = s_sq[nt];
            s += __shfl_xor(s, 16); q += __shfl_xor(q, 16);
            s += __shfl_xor(s, 32); q += __shfl_xor(q, 32);
            if (quad == 0) {
                int colg = n0 + nt * 16 + l15;
                atomicAdd(&sums[rep * N + colg], s);
                atomicAdd(&sumsq[rep * N + colg], q);
            }
        }
    }
}

extern "C" void kernel_launch(void* const* d_in, const int* in_sizes, int n_in,
                              void* d_out, int out_size, void* d_ws, size_t ws_size,
                              hipStream_t stream) {
    const float* pre   = (const float*)d_in[0];
    const int*   ei    = (const int*)d_in[1];
    const float* W0    = (const float*)d_in[2];
    const float* b0    = (const float*)d_in[3];
    const float* W1    = (const float*)d_in[4];
    const float* b1    = (const float*)d_in[5];
    const float* g1    = (const float*)d_in[6];
    const float* beta1 = (const float*)d_in[7];
    const float* W2    = (const float*)d_in[8];
    const float* b2    = (const float*)d_in[9];
    const float* gf    = (const float*)d_in[10];
    const float* betaf = (const float*)d_in[11];

    char* p = (char*)d_ws;
    ushort_t* preb = (ushort_t*)p; p += (size_t)M_PAD * DIN * 2;
    ushort_t* ACT1 = (ushort_t*)p; p += (size_t)M_PAD * DD * 2;
    ushort_t* ACT2 = (ushort_t*)p; p += (size_t)M_PAD * DD * 2;
    ushort_t* H1   = (ushort_t*)p; p += (size_t)M_PAD * D2 * 2;
    ushort_t* W0T  = (ushort_t*)p; p += (size_t)DIN * DD * 2;
    ushort_t* W1T  = (ushort_t*)p; p += (size_t)NLAYERS * DD * D2 * 2;
    ushort_t* W2T  = (ushort_t*)p; p += (size_t)NLAYERS * D2 * DD * 2;
    // stats replica slabs — must stay contiguous (prep zeroes them as one range)
    float* sums1  = (float*)p; p += (size_t)NREP * D2 * 4;
    float* sumsq1 = (float*)p; p += (size_t)NREP * D2 * 4;
    float* sumsF  = (float*)p; p += (size_t)NREP * DD * 4;
    float* sumsqF = (float*)p; p += (size_t)NREP * DD * 4;
    float* ca1    = (float*)p; p += D2 * 4;
    float* cc1    = (float*)p; p += D2 * 4;
    float* caf    = (float*)p; p += DD * 4;
    float* ccf    = (float*)p; p += DD * 4;
    float2* cacc1 = (float2*)p; p += D2 * 8;
    int* deg    = (int*)p; p += (size_t)MNODES * 4;
    int* rowptr = (int*)p; p += (size_t)(MNODES + 1) * 4;
    int* cursor = (int*)p; p += (size_t)MNODES * 4;
    int* colx   = (int*)p; p += (size_t)NEDGES * 4;
    int* bsum   = (int*)p; p += 256 * 4;

    dim3 blk(256);
    dim3 blk2(512);
    const int mb2 = (MNODES + 255) / 256;       // 196 (256-row tiles)
    const int nsb = (MNODES + 255) / 256;       // 196

    const int prep_rest = 256 + NSTATZ + MNODES;
    k_prep_all<<<NWTB + NCASTB + (prep_rest + 255) / 256, blk, 0, stream>>>(
        pre, preb, W0, W1, W2, W0T, W1T, W2T, caf, ccf, sums1, deg);

    k_hist<<<(NEDGES + 255) / 256, blk, 0, stream>>>(ei, deg);
    k_scan1<<<nsb, blk, 0, stream>>>(deg, rowptr, bsum, MNODES);
    k_scan2<<<1, blk, 0, stream>>>(bsum, nsb);
    k_scan3<<<nsb, blk, 0, stream>>>(deg, bsum, rowptr, cursor, MNODES);
    k_fill<<<(NEDGES + 255) / 256, blk, 0, stream>>>(ei, cursor, colx);

    // X0 = pre @ W0 + b0  -> ACT2
    k_gemm_bf<0, 0, 0, DIN><<<dim3(DD / 128, mb2), blk2, 0, stream>>>(
        preb, W0T, b0, nullptr, nullptr, nullptr, nullptr,
        ACT2, nullptr, nullptr, MNODES, DD);

    for (int l = 0; l < NLAYERS; l++) {
        // ACT1 = caf*(ACT2[n] + sum ACT2[src]) + (deg+1)*ccf
        k_gather<<<MNODES / 4, blk, 0, stream>>>(rowptr, colx, ACT2, caf, ccf, ACT1);

        // H1 = ACT1 @ W1 + b1 (raw, pre-BN), fused column stats
        k_gemm_bf<1, 0, 0, DD><<<dim3(D2 / 128, mb2), blk2, 0, stream>>>(
            ACT1, W1T + (size_t)l * DD * D2, b1 + (size_t)l * D2,
            nullptr, nullptr, nullptr, nullptr,
            H1, sums1, sumsq1, MNODES, D2);
        k_coeffs<<<2, blk, 0, stream>>>(sums1, sumsq1, g1 + (size_t)l * D2,
                                        beta1 + (size_t)l * D2, ca1, cc1, cacc1, D2);

        // ACT2 = relu(bn1(H1)) @ W2 + b2 + bn_prev(ACT2)
        k_gemm_bf<1, 1, 1, D2><<<dim3(DD / 128, mb2), blk2, 0, stream>>>(
            H1, W2T + (size_t)l * D2 * DD, b2 + (size_t)l * DD,
            ACT2, caf, ccf, cacc1,
            ACT2, sumsF, sumsqF, MNODES, DD);
        k_coeffs<<<1, blk, 0, stream>>>(sumsF, sumsqF, gf + (size_t)l * DD,
                                        betaf + (size_t)l * DD, caf, ccf, nullptr, DD);
    }

    // d_out = caf*ACT2 + ccf  (fp32)
    k_apply_out<<<(MNODES * 64) / 256, blk, 0, stream>>>(ACT2, caf, ccf, (float*)d_out);
}

// Round 13
// 740.681 us; speedup vs baseline: 1.0657x; 1.0657x over previous
//
#include <hip/hip_runtime.h>

#define MNODES 50000
#define M_PAD  50048          // 391 * 128
#define NEDGES 800000
#define DIN    128
#define DD     256
#define D2     512
#define NLAYERS 3
#define BN_EPS 1e-5f
#define NREP   16             // stats replica rows (contention spreader)

typedef unsigned short ushort_t;
typedef __bf16 v8bf __attribute__((ext_vector_type(8)));
typedef unsigned short v8us __attribute__((ext_vector_type(8)));
typedef float  v4f  __attribute__((ext_vector_type(4)));

#define GLOBAL_AS __attribute__((address_space(1)))
#define LDS_AS    __attribute__((address_space(3)))

__device__ __forceinline__ float bf2f(ushort_t u) {
    unsigned x = ((unsigned)u) << 16;
    return __uint_as_float(x);
}
__device__ __forceinline__ ushort_t f2bf(float f) {
    unsigned u = __float_as_uint(f);
    u += 0x7FFF + ((u >> 16) & 1);   // RNE
    return (ushort_t)(u >> 16);
}
__device__ __forceinline__ void async16(const ushort_t* g, ushort_t* l) {
    __builtin_amdgcn_global_load_lds((const GLOBAL_AS unsigned int*)g,
                                     (LDS_AS unsigned int*)l, 16, 0, 0);
}
// bijective XCD-chunked remap (neutral-measured r11; kept, harmless)
__device__ __forceinline__ int xcd_chunk(int b, int nb) {
    int q = nb >> 3, r = nb & 7, x = b & 7, s = b >> 3;
    return (x < r ? x * (q + 1) : r * (q + 1) + (x - r) * q) + s;
}
#define BARRIER() asm volatile("s_barrier" ::: "memory")
#define VMWAIT8() asm volatile("s_waitcnt vmcnt(8)" ::: "memory")
#define VMWAIT4() asm volatile("s_waitcnt vmcnt(4)" ::: "memory")
#define VMWAIT0() asm volatile("s_waitcnt vmcnt(0)" ::: "memory")
#define LGKM0()   asm volatile("s_waitcnt lgkmcnt(0)" ::: "memory")

// ------- fused prep: weight transpose tiles (blocks 0..799) + bf16 cast + inits
#define R0 (M_PAD * DIN)                       // 6406144
#define R0V (R0 / 4)                           // 1601536 (float4/ushort4 path)
#define NCASTB (R0V / 256)                     // 6256 cast blocks (exact)
// per-layer stat slabs (no re-zero needed): 3*(16*512*2 + 16*256*2) floats
#define NSTATZ (NLAYERS * (NREP * D2 * 2 + NREP * DD * 2))  // 73728
#define NWTB 800                               // 32 + 3*128 + 3*128 transpose tiles
__global__ __launch_bounds__(256)
void k_prep_all(const float* __restrict__ pre, ushort_t* __restrict__ preb,
                const float* __restrict__ W0, const float* __restrict__ W1,
                const float* __restrict__ W2, ushort_t* __restrict__ W0T,
                ushort_t* __restrict__ W1T, ushort_t* __restrict__ W2T,
                float* __restrict__ caf, float* __restrict__ ccf,
                float* __restrict__ statz, int* __restrict__ deg) {
    __shared__ float tl[32][33];
    if (blockIdx.x < NWTB) {       // 32x32 LDS-tiled transpose, coalesced both sides
        int tile = blockIdx.x;
        const float* src; ushort_t* dst; int K, N;
        if (tile < 32) {
            src = W0; dst = W0T; K = DIN; N = DD;
        } else if (tile < 416) {
            int t2 = tile - 32, l = t2 >> 7; t2 &= 127;
            src = W1 + (size_t)l * DD * D2; dst = W1T + (size_t)l * DD * D2;
            K = DD; N = D2; tile = t2;
        } else {
            int t2 = tile - 416, l = t2 >> 7; t2 &= 127;
            src = W2 + (size_t)l * D2 * DD; dst = W2T + (size_t)l * D2 * DD;
            K = D2; N = DD; tile = t2;
        }
        int ntn = N >> 5;
        int kt = tile / ntn, nt = tile - kt * ntn;
        int tx = threadIdx.x & 31, ty = threadIdx.x >> 5;   // 8 rows/phase
        #pragma unroll
        for (int r = 0; r < 4; r++)
            tl[ty + 8 * r][tx] = src[(size_t)(kt * 32 + ty + 8 * r) * N + nt * 32 + tx];
        __syncthreads();
        #pragma unroll
        for (int r = 0; r < 4; r++)
            dst[(size_t)(nt * 32 + ty + 8 * r) * K + kt * 32 + tx] =
                f2bf(tl[tx][ty + 8 * r]);
        return;
    }
    int b2 = blockIdx.x - NWTB;
    if (b2 < NCASTB) {              // cast, XCD-chunked
        int i = xcd_chunk(b2, NCASTB) * 256 + threadIdx.x;
        int row = i >> 5;           // 32 ushort4 per row
        ushort4 o;
        if (row < MNODES) {
            float4 v = ((const float4*)pre)[i];
            o.x = f2bf(v.x); o.y = f2bf(v.y); o.z = f2bf(v.z); o.w = f2bf(v.w);
        } else {
            o.x = 0; o.y = 0; o.z = 0; o.w = 0;
        }
        ((ushort4*)preb)[i] = o;
        return;
    }
    int j = (b2 - NCASTB) * 256 + threadIdx.x;
    if (j < 256) { caf[j] = 1.f; ccf[j] = 0.f; return; }
    j -= 256;
    if (j < NSTATZ) { statz[j] = 0.f; return; }
    j -= NSTATZ;
    if (j < MNODES) deg[j] = 0;
}

// ---------------- CSR build ----------------
__global__ void k_hist(const int* __restrict__ ei, int* __restrict__ deg) {
    int e = blockIdx.x * blockDim.x + threadIdx.x;
    if (e < NEDGES) atomicAdd(&deg[ei[e * 2 + 1]], 1);
}
__global__ void k_scan1(const int* __restrict__ deg, int* __restrict__ rowptr,
                        int* __restrict__ bsum, int n) {
    __shared__ int tmp[256];
    int tid = threadIdx.x;
    int i = blockIdx.x * 256 + tid;
    int v = (i < n) ? deg[i] : 0;
    tmp[tid] = v;
    __syncthreads();
    #pragma unroll
    for (int off = 1; off < 256; off <<= 1) {
        int t = (tid >= off) ? tmp[tid - off] : 0;
        __syncthreads();
        tmp[tid] += t;
        __syncthreads();
    }
    if (i < n) rowptr[i + 1] = tmp[tid];
    if (tid == 255) bsum[blockIdx.x] = tmp[255];
}
__global__ __launch_bounds__(256)
void k_scan2(int* __restrict__ bsum, int nb) {
    __shared__ int tmp[256];
    int tid = threadIdx.x;
    int v = (tid < nb) ? bsum[tid] : 0;
    tmp[tid] = v;
    __syncthreads();
    #pragma unroll
    for (int off = 1; off < 256; off <<= 1) {
        int t = (tid >= off) ? tmp[tid - off] : 0;
        __syncthreads();
        tmp[tid] += t;
        __syncthreads();
    }
    if (tid < nb) bsum[tid] = tmp[tid] - v;
}
__global__ void k_scan3(const int* __restrict__ deg, const int* __restrict__ bsum,
                        int* __restrict__ rowptr, int* __restrict__ cursor, int n) {
    int i = blockIdx.x * 256 + threadIdx.x;
    if (i == 0) rowptr[0] = 0;
    if (i < n) {
        int incl = rowptr[i + 1] + bsum[i >> 8];
        rowptr[i + 1] = incl;
        cursor[i] = incl - deg[i];
    }
}
__global__ void k_fill(const int* __restrict__ ei, int* __restrict__ cursor,
                       int* __restrict__ col) {
    int e = blockIdx.x * blockDim.x + threadIdx.x;
    if (e < NEDGES) {
        int pos = atomicAdd(&cursor[ei[e * 2 + 1]], 1);
        col[pos] = ei[e * 2];
    }
}

// --- gather: out = ca*(x[n] + sum x[src]) + (deg+1)*cc; masked 8-deep loop ---
__global__ void k_gather(const int* __restrict__ rowptr, const int* __restrict__ col,
                         const ushort_t* __restrict__ x, const float* __restrict__ ca,
                         const float* __restrict__ cc, ushort_t* __restrict__ out) {
    int node = xcd_chunk(blockIdx.x, MNODES / 4) * 4 + (threadIdx.x >> 6);
    int lane = threadIdx.x & 63;
    if (node >= MNODES) return;
    const ushort4* xp = (const ushort4*)x;
    ushort4 v = xp[(size_t)node * 64 + lane];
    float a0 = bf2f(v.x), a1 = bf2f(v.y), a2 = bf2f(v.z), a3 = bf2f(v.w);
    int s = rowptr[node], e = rowptr[node + 1];
    for (int i = s; i < e; i += 8) {
        ushort4 u[8];
        float m[8];
        #pragma unroll
        for (int j = 0; j < 8; j++) {
            int idx = i + j;
            int cj = col[idx < e ? idx : e - 1];   // e>s inside loop -> e-1 valid
            m[j] = (idx < e) ? 1.f : 0.f;
            u[j] = xp[(size_t)cj * 64 + lane];
        }
        #pragma unroll
        for (int j = 0; j < 8; j++) {
            a0 = fmaf(m[j], bf2f(u[j].x), a0);
            a1 = fmaf(m[j], bf2f(u[j].y), a1);
            a2 = fmaf(m[j], bf2f(u[j].z), a2);
            a3 = fmaf(m[j], bf2f(u[j].w), a3);
        }
    }
    int c = lane * 4;
    float dn = (float)(e - s) + 1.0f;
    ushort4 o;
    o.x = f2bf(ca[c + 0] * a0 + dn * cc[c + 0]);
    o.y = f2bf(ca[c + 1] * a1 + dn * cc[c + 1]);
    o.z = f2bf(ca[c + 2] * a2 + dn * cc[c + 2]);
    o.w = f2bf(ca[c + 3] * a3 + dn * cc[c + 3]);
    ((ushort4*)out)[(size_t)node * 64 + lane] = o;
}

// ---- BN coeffs (sumsF path only): fold NREP replicas, read-only slabs ----
__global__ void k_coeffs(const float* __restrict__ sums, const float* __restrict__ sumsq,
                         const float* __restrict__ g, const float* __restrict__ beta,
                         float* __restrict__ ca, float* __restrict__ cc, int n) {
    int c = blockIdx.x * blockDim.x + threadIdx.x;
    if (c >= n) return;
    float s = 0.f, q = 0.f;
    #pragma unroll
    for (int r = 0; r < NREP; r++) {
        s += sums[r * n + c];
        q += sumsq[r * n + c];
    }
    float mean = s * (1.0f / MNODES);
    float var  = q * (1.0f / MNODES) - mean * mean;
    float a    = g[c] * rsqrtf(var + BN_EPS);
    ca[c] = a;
    cc[c] = beta[c] - a * mean;
}

// ------ final: d_out = ca*h + cc (fp32) ------
__global__ void k_apply_out(const ushort_t* __restrict__ h, const float* __restrict__ ca,
                            const float* __restrict__ cc, float* __restrict__ out) {
    int i = xcd_chunk(blockIdx.x, (MNODES * 64) / 256) * 256 + threadIdx.x;
    int c = (i & 63) * 4;
    ushort4 v = ((const ushort4*)h)[i];
    float4 o;
    o.x = ca[c + 0] * bf2f(v.x) + cc[c + 0];
    o.y = ca[c + 1] * bf2f(v.y) + cc[c + 1];
    o.z = ca[c + 2] * bf2f(v.z) + cc[c + 2];
    o.w = ca[c + 3] * bf2f(v.w) + cc[c + 3];
    ((float4*)out)[i] = o;
}

// ---- B-dbuf bf16 MFMA GEMM, 128x128 tile (r7/r11 verbatim schedule — best of
// 10 measured variants). NEW in r13: FUSE_BN folds the BN1 stats replicas
// itself (same ascending-r FP order as k_coeffs -> bitwise-identical coeffs),
// eliminating the 3 BN1 k_coeffs dispatches. The fold's global loads are
// consumed (hence retired) before the A/B issue section, so the counted-vmcnt
// arithmetic (VMWAIT4/VMWAIT8) is unchanged.
#define LOADA(buf, st)                                                        \
    { buf[0] = *(const v8bf*)(Ap + (st) * 32);                                \
      buf[1] = *(const v8bf*)(Ap + 16 * KT + (st) * 32); }

template<int DO_STATS, int RES, int FUSE_BN, int KT>
__global__ __launch_bounds__(256, 3)
void k_gemm_bf(const ushort_t* __restrict__ A, const ushort_t* __restrict__ WT,
               const float* __restrict__ bias,
               const ushort_t* resid, const float* __restrict__ r_ca,
               const float* __restrict__ r_cc,
               const float* __restrict__ s1s, const float* __restrict__ s1q,
               const float* __restrict__ gg, const float* __restrict__ bbeta,
               ushort_t* out, float* __restrict__ sums, float* __restrict__ sumsq,
               int M, int N) {
    static_assert(KT % 128 == 0, "KT multiple of 128");
    constexpr int nk  = KT >> 5;         // K-steps: 4, 8, 16
    constexpr int nc2 = KT >> 6;         // 64k chunks: 2, 4, 8
    __shared__ __align__(16) ushort_t Bs[2][128 * 64];   // 2 x 16 KB
    const int tid = threadIdx.x;
    const int w = tid >> 6, lane = tid & 63;
    const int quad = lane >> 4, l15 = lane & 15;

    // bijective XCD-chunked swizzle
    const int nxb = N >> 7;                         // 2 or 4 (power of two)
    const int nwg = nxb * (int)gridDim.y;
    const int orig = (int)blockIdx.y * nxb + (int)blockIdx.x;
    const int swz = xcd_chunk(orig, nwg);
    const int bx = swz & (nxb - 1);
    const int by = (nxb == 4) ? (swz >> 2) : (swz >> 1);
    const int m0 = by * 128, n0 = bx * 128;

    // FUSE_BN: fold BN1 stats replicas -> (ca,cc) into LDS (per-block,
    // redundant, L2-hot; same FP order as the old k_coeffs kernel).
    float2* cacc_lds = nullptr;
    if constexpr (FUSE_BN != 0) {
        __shared__ __align__(16) float2 cacc_s[KT];
        cacc_lds = cacc_s;
        #pragma unroll
        for (int c2 = tid; c2 < KT; c2 += 256) {
            float s = 0.f, q = 0.f;
            #pragma unroll
            for (int r = 0; r < NREP; r++) {
                s += s1s[r * KT + c2];
                q += s1q[r * KT + c2];
            }
            float mean = s * (1.0f / MNODES);
            float var  = q * (1.0f / MNODES) - mean * mean;
            float a    = gg[c2] * rsqrtf(var + BN_EPS);
            cacc_lds[c2] = make_float2(a, bbeta[c2] - a * mean);
        }
        // ds_writes drained by LGKM0 below; published by prologue barrier
    }

    // B DMA sources: per wave 4 issues/chunk; issue ii = w*4+j covers rows
    // ii*8 + (lane>>3); lane slot lane&7 holds global chunk (lane&7)^(row&7).
    const ushort_t* srcB[4];
    {
        int r8 = lane >> 3, s8 = lane & 7;
        #pragma unroll
        for (int j = 0; j < 4; j++) {
            int rowb = (w * 4 + j) * 8 + r8;
            int g = s8 ^ (rowb & 7);
            srcB[j] = WT + (size_t)(n0 + rowb) * KT + g * 8;
        }
    }

    // per-wave private A strip: rows m0 + w*32 .. +32
    const ushort_t* Ap = A + (size_t)(m0 + w * 32 + l15) * KT + quad * 8;

    v4f acc[2][8];
    #pragma unroll
    for (int i = 0; i < 2; i++)
        #pragma unroll
        for (int j = 0; j < 8; j++)
            acc[i][j] = (v4f){0.f, 0.f, 0.f, 0.f};

    // A prologue: 4-slot ring holds steps 0..3 (nk >= 4 always)
    v8bf a0[2], a1[2], a2[2], a3[2];
    LOADA(a0, 0) LOADA(a1, 1) LOADA(a2, 2) LOADA(a3, 3)

    // B prologue: chunks 0 and 1 (nc2 >= 2 always)
    #pragma unroll
    for (int j = 0; j < 4; j++) async16(srcB[j], &Bs[0][(w * 4 + j) * 512]);
    #pragma unroll
    for (int j = 0; j < 4; j++) async16(srcB[j] + 64, &Bs[1][(w * 4 + j) * 512]);
    if constexpr (FUSE_BN != 0) { LGKM0(); }
    VMWAIT4();                    // drain A + chunk0; chunk1 stays in flight
    BARRIER();

    #pragma unroll
    for (int c = 0; c < nc2; c++) {
        if (c > 0) {
            BARRIER();            // all waves done reading Bs[(c-1)&1] — freed
            if (c + 1 < nc2) {
                #pragma unroll
                for (int j = 0; j < 4; j++)
                    async16(srcB[j] + (c + 1) * 64, &Bs[(c + 1) & 1][(w * 4 + j) * 512]);
                VMWAIT8();        // chunk c's DMAs (oldest 4) complete
            } else {
                VMWAIT0();        // last chunk: full drain
            }
            BARRIER();            // chunk c visible to all waves
        }
        const ushort_t* Bb = Bs[c & 1];
        #pragma unroll
        for (int tc = 0; tc < 2; tc++) {
            const int s = c * 2 + tc;
            const int sl4 = s & 3;
            v8bf aUse[2];
            if (sl4 == 0)      { aUse[0] = a0[0]; aUse[1] = a0[1]; }
            else if (sl4 == 1) { aUse[0] = a1[0]; aUse[1] = a1[1]; }
            else if (sl4 == 2) { aUse[0] = a2[0]; aUse[1] = a2[1]; }
            else               { aUse[0] = a3[0]; aUse[1] = a3[1]; }
            if (s + 4 < nk) {
                if (sl4 == 0)      { LOADA(a0, s + 4) }
                else if (sl4 == 1) { LOADA(a1, s + 4) }
                else if (sl4 == 2) { LOADA(a2, s + 4) }
                else               { LOADA(a3, s + 4) }
            }
            if constexpr (FUSE_BN != 0) {
                const float* cb = (const float*)&cacc_lds[(s << 5) + (quad << 3)];
                #pragma unroll
                for (int mt = 0; mt < 2; mt++) {
                    v8us au = *(v8us*)&aUse[mt];
                    v8bf o;
                    #pragma unroll
                    for (int j = 0; j < 8; j++) {
                        float h = bf2f(au[j]);
                        o[j] = (__bf16)fmaxf(fmaf(cb[2 * j], h, cb[2 * j + 1]), 0.f);
                    }
                    aUse[mt] = o;
                }
            }
            v8bf bb0[4];
            #pragma unroll
            for (int nt = 0; nt < 4; nt++) {
                int n_l = nt * 16 + l15;
                int slot = (tc * 4 + quad) ^ (n_l & 7);
                bb0[nt] = *(const v8bf*)&Bb[n_l * 64 + slot * 8];
            }
            #pragma unroll
            for (int mt = 0; mt < 2; mt++)
                #pragma unroll
                for (int nt = 0; nt < 4; nt++)
                    acc[mt][nt] = __builtin_amdgcn_mfma_f32_16x16x32_bf16(
                        aUse[mt], bb0[nt], acc[mt][nt], 0, 0, 0);
            v8bf bb1[4];
            #pragma unroll
            for (int nt = 0; nt < 4; nt++) {
                int n_l = (nt + 4) * 16 + l15;
                int slot = (tc * 4 + quad) ^ (n_l & 7);
                bb1[nt] = *(const v8bf*)&Bb[n_l * 64 + slot * 8];
            }
            #pragma unroll
            for (int mt = 0; mt < 2; mt++)
                #pragma unroll
                for (int nt = 0; nt < 4; nt++)
                    acc[mt][nt + 4] = __builtin_amdgcn_mfma_f32_16x16x32_bf16(
                        aUse[mt], bb1[nt], acc[mt][nt + 4], 0, 0, 0);
        }
    }

    // epilogue: bias (+ lazy-BN residual) -> bf16 store + fused column stats
    const int mlim = M - m0;
    float s_sum[8], s_sq[8];
    #pragma unroll
    for (int nt = 0; nt < 8; nt++) { s_sum[nt] = 0.f; s_sq[nt] = 0.f; }
    #pragma unroll
    for (int nt = 0; nt < 8; nt++) {
        int colg = n0 + nt * 16 + l15;
        float bia = bias[colg];
        float rca = 0.f, rcc = 0.f;
        if (RES) { rca = r_ca[colg]; rcc = r_cc[colg]; }
        #pragma unroll
        for (int mt = 0; mt < 2; mt++) {
            int rbase = w * 32 + mt * 16 + quad * 4;
            #pragma unroll
            for (int r = 0; r < 4; r++) {
                int rl = rbase + r;
                if (rl < mlim) {
                    size_t idx = (size_t)(m0 + rl) * N + colg;
                    float v = acc[mt][nt][r] + bia;
                    if (RES) v += rca * bf2f(resid[idx]) + rcc;
                    out[idx] = f2bf(v);
                    if (DO_STATS) { s_sum[nt] += v; s_sq[nt] += v * v; }
                }
            }
        }
    }
    if (DO_STATS) {
        const int rep = (by * 4 + w) & (NREP - 1);
        #pragma unroll
        for (int nt = 0; nt < 8; nt++) {
            float s = s_sum[nt], q = s_sq[nt];
            s += __shfl_xor(s, 16); q += __shfl_xor(q, 16);
            s += __shfl_xor(s, 32); q += __shfl_xor(q, 32);
            if (quad == 0) {
                int colg = n0 + nt * 16 + l15;
                atomicAdd(&sums[rep * N + colg], s);
                atomicAdd(&sumsq[rep * N + colg], q);
            }
        }
    }
}

extern "C" void kernel_launch(void* const* d_in, const int* in_sizes, int n_in,
                              void* d_out, int out_size, void* d_ws, size_t ws_size,
                              hipStream_t stream) {
    const float* pre   = (const float*)d_in[0];
    const int*   ei    = (const int*)d_in[1];
    const float* W0    = (const float*)d_in[2];
    const float* b0    = (const float*)d_in[3];
    const float* W1    = (const float*)d_in[4];
    const float* b1    = (const float*)d_in[5];
    const float* g1    = (const float*)d_in[6];
    const float* beta1 = (const float*)d_in[7];
    const float* W2    = (const float*)d_in[8];
    const float* b2    = (const float*)d_in[9];
    const float* gf    = (const float*)d_in[10];
    const float* betaf = (const float*)d_in[11];

    char* p = (char*)d_ws;
    ushort_t* preb = (ushort_t*)p; p += (size_t)M_PAD * DIN * 2;
    ushort_t* ACT1 = (ushort_t*)p; p += (size_t)M_PAD * DD * 2;
    ushort_t* ACT2 = (ushort_t*)p; p += (size_t)M_PAD * DD * 2;
    ushort_t* H1   = (ushort_t*)p; p += (size_t)M_PAD * D2 * 2;
    ushort_t* W0T  = (ushort_t*)p; p += (size_t)DIN * DD * 2;
    ushort_t* W1T  = (ushort_t*)p; p += (size_t)NLAYERS * DD * D2 * 2;
    ushort_t* W2T  = (ushort_t*)p; p += (size_t)NLAYERS * D2 * DD * 2;
    // per-layer stat slabs — contiguous (prep zeroes them as one range)
    float* statz  = (float*)p;
    float* sums1  = (float*)p; p += (size_t)NLAYERS * NREP * D2 * 4;
    float* sumsq1 = (float*)p; p += (size_t)NLAYERS * NREP * D2 * 4;
    float* sumsF  = (float*)p; p += (size_t)NLAYERS * NREP * DD * 4;
    float* sumsqF = (float*)p; p += (size_t)NLAYERS * NREP * DD * 4;
    float* caf    = (float*)p; p += DD * 4;
    float* ccf    = (float*)p; p += DD * 4;
    int* deg    = (int*)p; p += (size_t)MNODES * 4;
    int* rowptr = (int*)p; p += (size_t)(MNODES + 1) * 4;
    int* cursor = (int*)p; p += (size_t)MNODES * 4;
    int* colx   = (int*)p; p += (size_t)NEDGES * 4;
    int* bsum   = (int*)p; p += 256 * 4;

    dim3 blk(256);
    const int mb = (MNODES + 127) / 128;        // 391
    const int nsb = (MNODES + 255) / 256;       // 196

    const int prep_rest = 256 + NSTATZ + MNODES;
    k_prep_all<<<NWTB + NCASTB + (prep_rest + 255) / 256, blk, 0, stream>>>(
        pre, preb, W0, W1, W2, W0T, W1T, W2T, caf, ccf, statz, deg);

    k_hist<<<(NEDGES + 255) / 256, blk, 0, stream>>>(ei, deg);
    k_scan1<<<nsb, blk, 0, stream>>>(deg, rowptr, bsum, MNODES);
    k_scan2<<<1, blk, 0, stream>>>(bsum, nsb);
    k_scan3<<<nsb, blk, 0, stream>>>(deg, bsum, rowptr, cursor, MNODES);
    k_fill<<<(NEDGES + 255) / 256, blk, 0, stream>>>(ei, cursor, colx);

    // X0 = pre @ W0 + b0  -> ACT2
    k_gemm_bf<0, 0, 0, DIN><<<dim3(DD / 128, mb), blk, 0, stream>>>(
        preb, W0T, b0, nullptr, nullptr, nullptr,
        nullptr, nullptr, nullptr, nullptr,
        ACT2, nullptr, nullptr, MNODES, DD);

    for (int l = 0; l < NLAYERS; l++) {
        float* s1s = sums1  + (size_t)l * NREP * D2;
        float* s1q = sumsq1 + (size_t)l * NREP * D2;
        float* sFs = sumsF  + (size_t)l * NREP * DD;
        float* sFq = sumsqF + (size_t)l * NREP * DD;

        // ACT1 = caf*(ACT2[n] + sum ACT2[src]) + (deg+1)*ccf
        k_gather<<<MNODES / 4, blk, 0, stream>>>(rowptr, colx, ACT2, caf, ccf, ACT1);

        // H1 = ACT1 @ W1 + b1 (raw, pre-BN), fused column stats (layer slab)
        k_gemm_bf<1, 0, 0, DD><<<dim3(D2 / 128, mb), blk, 0, stream>>>(
            ACT1, W1T + (size_t)l * DD * D2, b1 + (size_t)l * D2,
            nullptr, nullptr, nullptr,
            nullptr, nullptr, nullptr, nullptr,
            H1, s1s, s1q, MNODES, D2);

        // ACT2 = relu(bn1(H1)) @ W2 + b2 + bn_prev(ACT2)
        // (BN1 coeffs folded in-kernel from the layer slab; fused stats)
        k_gemm_bf<1, 1, 1, D2><<<dim3(DD / 128, mb), blk, 0, stream>>>(
            H1, W2T + (size_t)l * D2 * DD, b2 + (size_t)l * DD,
            ACT2, caf, ccf,
            s1s, s1q, g1 + (size_t)l * D2, beta1 + (size_t)l * D2,
            ACT2, sFs, sFq, MNODES, DD);
        k_coeffs<<<1, blk, 0, stream>>>(sFs, sFq, gf + (size_t)l * DD,
                                        betaf + (size_t)l * DD, caf, ccf, DD);
    }

    // d_out = caf*ACT2 + ccf  (fp32)
    k_apply_out<<<(MNODES * 64) / 256, blk, 0, stream>>>(ACT2, caf, ccf, (float*)d_out);
}